// Round 2
// baseline (45.760 us; speedup 1.0000x reference)
//
#include <hip/hip_runtime.h>
#include <math.h>

#define SEARCH 7
#define PAD 3
#define S2 49
#define KNN 7
#define NCLASSES 20
#define H 64
#define W 2048
#define NPTS 131072

struct InvG { float v[S2]; };

__device__ __forceinline__ void insert7(unsigned long long (&s)[KNN], unsigned long long key) {
    // sorted ascending; keys are unique -> strict < gives exact lex-(dist, j) order
    bool c0 = key < s[0], c1 = key < s[1], c2 = key < s[2], c3 = key < s[3],
         c4 = key < s[4], c5 = key < s[5], c6 = key < s[6];
    s[6] = c6 ? (c5 ? s[5] : key) : s[6];
    s[5] = c5 ? (c4 ? s[4] : key) : s[5];
    s[4] = c4 ? (c3 ? s[3] : key) : s[4];
    s[3] = c3 ? (c2 ? s[2] : key) : s[3];
    s[2] = c2 ? (c1 ? s[1] : key) : s[2];
    s[1] = c1 ? (c0 ? s[0] : key) : s[1];
    s[0] = c0 ? key : s[0];
}

__global__ __launch_bounds__(256) void knn_kernel(
    const float* __restrict__ proj_range,
    const float* __restrict__ unproj_range,
    const int* __restrict__ proj_argmax,
    const int* __restrict__ pxv,
    const int* __restrict__ pyv,
    int* __restrict__ outv,
    InvG invg)
{
    int tid  = blockIdx.x * blockDim.x + threadIdx.x;
    int lane = threadIdx.x & 63;
    bool half = (lane >> 5) != 0;              // lanes 0-31: j 0..23; lanes 32-63: j 24..48
    int wave = tid >> 6;
    int point = wave * 32 + (lane & 31);       // grid sized exactly: point < NPTS

    int x = pxv[point];
    int y = pyv[point];
    float u = unproj_range[point];

    unsigned long long keys[KNN];
#pragma unroll
    for (int k = 0; k < KNN; ++k) keys[k] = ~0ull;

    // B-half free center candidate: dist = 0 exactly -> key = (0<<6)|24
    {
        unsigned long long ckey = half ? 24ull : ~0ull;   // sentinel never inserts
        insert7(keys, ckey);
    }

#pragma unroll
    for (int s = 0; s < 24; ++s) {
        const int jA = s,        jB = s + 25;
        const int dyA = jA / 7 - PAD, dxA = jA % 7 - PAD;
        const int dyB = jB / 7 - PAD, dxB = jB % 7 - PAD;
        int dy = half ? dyB : dyA;
        int dx = half ? dxB : dxA;
        int j  = half ? jB  : jA;
        float ig = half ? invg.v[jB] : invg.v[jA];

        int row = y + dy;
        int rc  = min(max(row, 0), H - 1);
        int col = x + dx;
        col += (col < 0) ? W : 0;
        col -= (col >= W) ? W : 0;
        float nb = proj_range[rc * W + col];          // clamped address: always safe
        nb = (row == rc) ? nb : 0.0f;                 // zero-pad outside H
        nb = (nb < 0.0f) ? __builtin_inff() : nb;
        float d = fabsf(nb - u) * ig;
        unsigned long long key =
            ((unsigned long long)__float_as_uint(d) << 6) | (unsigned)j;
        insert7(keys, key);
    }

    // exchange with partner lane (lane ^ 32) while all lanes active
    unsigned long long other[KNN];
#pragma unroll
    for (int k = 0; k < KNN; ++k)
        other[k] = __shfl_xor(keys[k], 32, 64);

    // Batcher half-cleaner: mins of (a_i, b_{6-i}) = the 7 smallest of the 14 (keys unique)
    unsigned long long m[KNN];
#pragma unroll
    for (int k = 0; k < KNN; ++k) {
        unsigned long long bb = other[6 - k];
        m[k] = keys[k] < bb ? keys[k] : bb;
    }

    if (lane < 32) {
        // gather classes for winners; dist > 1.0f (incl. sentinel) -> no vote
        int cls[KNN];
#pragma unroll
        for (int k = 0; k < KNN; ++k) {
            unsigned long long key = m[k];
            int j = (int)(key & 63u);
            bool sel = (key >> 6) <= 0x3f800000ull;    // dist <= CUTOFF
            int dy7 = (j * 37) >> 8;                   // j/7 for j in [0,55]
            int row = y + dy7 - PAD;
            bool vrow = (unsigned)row < (unsigned)H;
            int rc  = min(max(row, 0), H - 1);
            int col = x + (j - dy7 * 7 - PAD);
            col += (col < 0) ? W : 0;
            col -= (col >= W) ? W : 0;
            int c = proj_argmax[rc * W + col];
            cls[k] = (sel && vrow) ? c : 0;
        }

        // pairwise vote count; score = (cnt<<5)|(31-cls) so ties -> lowest class
        int cnt[KNN];
#pragma unroll
        for (int k = 0; k < KNN; ++k) cnt[k] = 1;
#pragma unroll
        for (int a = 0; a < KNN; ++a)
#pragma unroll
            for (int b = a + 1; b < KNN; ++b) {
                bool eq = (cls[a] == cls[b]);
                cnt[a] += eq ? 1 : 0;
                cnt[b] += eq ? 1 : 0;
            }
        int best = 0;
#pragma unroll
        for (int k = 0; k < KNN; ++k) {
            bool valid = (unsigned)(cls[k] - 1) < (unsigned)(NCLASSES - 1); // cls in [1,19]
            int score = valid ? ((cnt[k] << 5) | (31 - cls[k])) : 0;
            best = max(best, score);
        }
        int bestc = (best == 0) ? 1 : (31 - (best & 31));
        outv[point] = bestc;
    }
}

extern "C" void kernel_launch(void* const* d_in, const int* in_sizes, int n_in,
                              void* d_out, int out_size, void* d_ws, size_t ws_size,
                              hipStream_t stream) {
    const float* proj_range   = (const float*)d_in[0];
    const float* unproj_range = (const float*)d_in[1];
    const int*   proj_argmax  = (const int*)d_in[2];
    const int*   px           = (const int*)d_in[3];
    const int*   py           = (const int*)d_in[4];
    int* out = (int*)d_out;

    // Emulate numpy float32 pipeline for the inverse-gaussian table.
    InvG invg;
    float g[S2];
    for (int yy = 0; yy < SEARCH; ++yy) {
        for (int xx = 0; xx < SEARCH; ++xx) {
            float fdx = (float)xx - 3.0f;
            float fdy = (float)yy - 3.0f;
            float s   = fdx * fdx + fdy * fdy;
            float arg = -s / 2.0f;
            float e   = (float)exp((double)arg);
            float gg  = e / 6.2831855f;
            g[yy * SEARCH + xx] = gg;
        }
    }
    float r[8];
    for (int t = 0; t < 8; ++t) r[t] = g[t];
    int ii;
    for (ii = 8; ii + 8 <= 48; ii += 8)
        for (int t = 0; t < 8; ++t) r[t] += g[ii + t];
    float ssum = ((r[0] + r[1]) + (r[2] + r[3])) + ((r[4] + r[5]) + (r[6] + r[7]));
    for (; ii < S2; ++ii) ssum += g[ii];
    for (int t = 0; t < S2; ++t) invg.v[t] = 1.0f - (g[t] / ssum);

    const int block = 256;
    const int threads = 2 * NPTS;              // 2 threads per point
    const int grid = threads / block;          // 1024
    knn_kernel<<<grid, block, 0, stream>>>(proj_range, unproj_range, proj_argmax,
                                           px, py, out, invg);
}